// Round 3
// baseline (535.622 us; speedup 1.0000x reference)
//
#include <hip/hip_runtime.h>
#include <hip/hip_bf16.h>

#define NN 2048
#define FIN 256
#define FOUT 256
#define HH 8
#define NB 256    // grid blocks (1 per CU, all co-resident)
#define NT 1024   // threads per block (16 waves)

typedef short bhalf8 __attribute__((ext_vector_type(8)));   // 8 bf16
typedef float f32x4  __attribute__((ext_vector_type(4)));   // MFMA acc

__device__ __forceinline__ unsigned short f2b(float f) {
    __hip_bfloat16 h = __float2bfloat16(f);
    return *reinterpret_cast<unsigned short*>(&h);
}
__device__ __forceinline__ float b2f(unsigned short u) {
    __hip_bfloat16 h = *reinterpret_cast<__hip_bfloat16*>(&u);
    return __bfloat162float(h);
}

// Device-scope grid barrier: monotonic counter, leader spin, agent-scope
// atomics (same structure as ROCm's grid.sync). Requires all NB blocks
// co-resident: guaranteed by 1 block/CU (NB=256=CUs, 16 waves, <=128 VGPR).
__device__ __forceinline__ void gridbar(unsigned* bar, unsigned target) {
    __syncthreads();
    if (threadIdx.x == 0) {
        __threadfence();  // release all prior stores device-wide
        __hip_atomic_fetch_add(bar, 1u, __ATOMIC_ACQ_REL, __HIP_MEMORY_SCOPE_AGENT);
        while (__hip_atomic_load(bar, __ATOMIC_ACQUIRE, __HIP_MEMORY_SCOPE_AGENT) < target) {
            __builtin_amdgcn_s_sleep(8);
        }
        __threadfence();  // acquire: invalidate stale cached lines
    }
    __syncthreads();
}

union SharedU {
    struct { float xs[4][4][256]; float part[4][256]; } p1;          // 20 KB
    struct { float qs[512]; float red[4][4][16][4][8]; } p2;         // 34 KB
    struct { float qs[512]; } p3;                                    //  2 KB
    struct { float LT[64][68]; float mui[64], rii[64], muj[64], rsj[64]; } p7; // 18.4 KB
};

__global__ __launch_bounds__(NT, 4) void mega(
    const float* __restrict__ x,    const float* __restrict__ dist,
    const float* __restrict__ bond, const float* __restrict__ deg,
    const float* __restrict__ Wq,   const float* __restrict__ Wk,
    const float* __restrict__ Wv,   const float* __restrict__ wb,
    const float* __restrict__ wbc,  const float* __restrict__ wg,
    float* __restrict__ out0, float* __restrict__ out1,
    unsigned short* __restrict__ fbuf_c0,   // fbuf (P2/P3) then c0 (P5/P7)
    unsigned short* __restrict__ amb, unsigned short* __restrict__ ddb,
    unsigned short* __restrict__ vtb, unsigned short* __restrict__ unb,
    float* __restrict__ qk, float* __restrict__ D,
    float* __restrict__ rowsum, float* __restrict__ rowsq,
    unsigned* __restrict__ bar)
{
    __shared__ SharedU sh;
    const int gid = blockIdx.x;
    const int tid = threadIdx.x;

    // ================= P1: qk & vtb (4 groups of 256 thr; blocks 0..127)
    // blocks 128..255 zero D / rowsum / rowsq meanwhile.
    if (gid < 128) {
        const int g = tid >> 8, sub = tid & 255;
        const int ib = (gid*4 + g) * 4;               // node base, 4 nodes/group
        float (*xs)[256] = sh.p1.xs[g];
        #pragma unroll
        for (int n = 0; n < 4; ++n) xs[n][sub] = x[(long)(ib+n)*FIN + sub];
        __syncthreads();
        float a0 = 0.f, a1 = 0.f, a2 = 0.f, a3 = 0.f;
        #pragma unroll 4
        for (int c = 0; c < FIN; ++c) {
            const float wv = Wv[c*FOUT + sub];
            a0 = fmaf(xs[0][c], wv, a0); a1 = fmaf(xs[1][c], wv, a1);
            a2 = fmaf(xs[2][c], wv, a2); a3 = fmaf(xs[3][c], wv, a3);
        }
        // vT_bf16[f][k]: 4 consecutive k per thread (8B store, aligned: ib%4==0)
        ushort4 uv;
        uv.x = f2b(a0 * 0.0625f); uv.y = f2b(a1 * 0.0625f);
        uv.z = f2b(a2 * 0.0625f); uv.w = f2b(a3 * 0.0625f);
        *(ushort4*)&vtb[(long)sub*NN + ib] = uv;
        {
            const int n = sub >> 6, h = sub & 7, seg = (sub >> 3) & 7;
            float a = 0.f;
            for (int c = seg*32; c < seg*32 + 32; ++c)
                a = fmaf(xs[n][c], Wq[c*HH + h] + Wk[c*HH + h], a);
            sh.p1.part[g][sub] = a;
        }
        __syncthreads();
        if (sub < 32) {
            const int n = sub >> 3, h = sub & 7;
            float a = 0.f;
            #pragma unroll
            for (int s2 = 0; s2 < 8; ++s2) a += sh.p1.part[g][n*64 + s2*8 + h];
            qk[(ib+n)*HH + h] = a * (0.0625f * 0.35355339059327373f);
        }
    } else {
        const int tp = (gid - 128)*NT + tid;
        if      (tp < 16384) D[tp] = 0.f;
        else if (tp < 18432) rowsum[tp - 16384] = 0.f;
        else if (tp < 20480) rowsq [tp - 18432] = 0.f;
    }
    gridbar(bar, NB*1);

    // ================= P2: denoms + f-field + dd  (tile 64i x 256j per block)
    {
        const float cb = wb[0] * wbc[0];
        const float cg = wg[0];
        const int bx = gid & 7, by = gid >> 3;
        const int j0 = bx*256, i0 = by*64;
        const int w  = tid >> 6, lane = tid & 63;
        const int jb = w & 3,  tqh = w >> 2;
        const int jq = lane & 15, tql = lane >> 4;
        const int tq = tqh*4 + tql;                    // [0,16): i-subgroup
        const int j  = j0 + (jb*16 + jq)*4;
        if (tid < 512) sh.p2.qs[tid] = qk[i0*8 + tid];
        __syncthreads();
        float acc[4][8];
        #pragma unroll
        for (int jj = 0; jj < 4; ++jj)
            #pragma unroll
            for (int h = 0; h < 8; ++h) acc[jj][h] = 0.f;
        #pragma unroll
        for (int ii = 0; ii < 4; ++ii) {
            const int i = i0 + tq*4 + ii;
            const long idx = (long)i*NN + j;
            const float4 dv = *(const float4*)&dist[idx];
            const float4 bv = *(const float4*)&bond[idx];
            const float4 gv = *(const float4*)&deg[idx];
            ushort4 fb, db;
            fb.x = f2b((gv.x > 0.f) ? fmaf(cb, bv.x, cg*dv.x) : -__builtin_inff());
            fb.y = f2b((gv.y > 0.f) ? fmaf(cb, bv.y, cg*dv.y) : -__builtin_inff());
            fb.z = f2b((gv.z > 0.f) ? fmaf(cb, bv.z, cg*dv.z) : -__builtin_inff());
            fb.w = f2b((gv.w > 0.f) ? fmaf(cb, bv.w, cg*dv.w) : -__builtin_inff());
            db.x = f2b(-dv.x * gv.x); db.y = f2b(-dv.y * gv.y);
            db.z = f2b(-dv.z * gv.z); db.w = f2b(-dv.w * gv.w);
            *(ushort4*)&fbuf_c0[idx] = fb;
            *(ushort4*)&ddb[idx]     = db;
            float s[4];
            s[0] = b2f(fb.x); s[1] = b2f(fb.y); s[2] = b2f(fb.z); s[3] = b2f(fb.w);
            const float* qrow = &sh.p2.qs[(tq*4 + ii)*8];
            #pragma unroll
            for (int h = 0; h < 8; ++h) {
                const float q = qrow[h];
                #pragma unroll
                for (int jj = 0; jj < 4; ++jj) {
                    float r = q + s[jj];
                    r = fmaxf(r, 0.2f*r);
                    acc[jj][h] += __expf(r);     // masked: exp(-inf)=0
                }
            }
        }
        // reduce over tql (lane bits 4,5), then over tqh via LDS
        #pragma unroll
        for (int jj = 0; jj < 4; ++jj)
            #pragma unroll
            for (int h = 0; h < 8; ++h) {
                float v = acc[jj][h];
                v += __shfl_xor(v, 16, 64);
                v += __shfl_xor(v, 32, 64);
                acc[jj][h] = v;
            }
        if (tql == 0) {
            #pragma unroll
            for (int jj = 0; jj < 4; ++jj)
                #pragma unroll
                for (int h = 0; h < 8; ++h)
                    sh.p2.red[tqh][jb][jq][jj][h] = acc[jj][h];
        }
        __syncthreads();
        for (int p = tid; p < 2048; p += NT) {
            const int jl = p >> 3, h = p & 7;
            const int q4 = jl >> 2, jj = jl & 3;
            const int jb2 = q4 >> 4, jq2 = q4 & 15;
            const float ssum = sh.p2.red[0][jb2][jq2][jj][h] + sh.p2.red[1][jb2][jq2][jj][h]
                             + sh.p2.red[2][jb2][jq2][jj][h] + sh.p2.red[3][jb2][jq2][jj][h];
            atomicAdd(&D[(j0 + jl)*8 + h], ssum);
        }
    }
    gridbar(bar, NB*2);

    // ================= P3: attn_mean -> bf16 (same tile geometry as P2)
    {
        const int bx = gid & 7, by = gid >> 3;
        const int j0 = bx*256, i0 = by*64;
        const int w  = tid >> 6, lane = tid & 63;
        const int jb = w & 3,  tqh = w >> 2;
        const int jq = lane & 15, tql = lane >> 4;
        const int tq = tqh*4 + tql;
        const int j  = j0 + (jb*16 + jq)*4;
        if (tid < 512) sh.p3.qs[tid] = qk[i0*8 + tid];
        __syncthreads();
        float invD[4][8];
        #pragma unroll
        for (int jj = 0; jj < 4; ++jj)
            #pragma unroll
            for (int h = 0; h < 8; ++h)
                invD[jj][h] = 0.125f / fmaxf(D[(j + jj)*8 + h], 1e-30f);
        #pragma unroll
        for (int ii = 0; ii < 4; ++ii) {
            const int i = i0 + tq*4 + ii;
            const long idx = (long)i*NN + j;
            const ushort4 fb = *(const ushort4*)&fbuf_c0[idx];
            float s[4];
            s[0] = b2f(fb.x); s[1] = b2f(fb.y); s[2] = b2f(fb.z); s[3] = b2f(fb.w);
            float o[4] = {0.f, 0.f, 0.f, 0.f};
            const float* qrow = &sh.p3.qs[(tq*4 + ii)*8];
            #pragma unroll
            for (int h = 0; h < 8; ++h) {
                const float q = qrow[h];
                #pragma unroll
                for (int jj = 0; jj < 4; ++jj) {
                    float r = q + s[jj];
                    r = fmaxf(r, 0.2f*r);
                    o[jj] = fmaf(__expf(r), invD[jj][h], o[jj]);
                }
            }
            ushort4 ob;
            ob.x = f2b(o[0]); ob.y = f2b(o[1]); ob.z = f2b(o[2]); ob.w = f2b(o[3]);
            *(ushort4*)&amb[idx] = ob;
        }
    }
    gridbar(bar, NB*3);

    // ================= P4: aggregated = amb @ vtb^T, + elu -> out0, unb
    // 2048 virtual waves: 16i x 16f tile, full K. Blocks 0..127 active.
    {
        const int w = tid >> 6, lane = tid & 63;
        const int vw = gid*16 + w;
        if (vw < 2048) {
            const int it = vw >> 4;                 // [0,128) i-tile
            const int f0 = (vw & 15) * 16;          // f-tile
            const int lm = lane & 15, lq = lane >> 4;
            const unsigned short* arow = &amb[(long)(it*16 + lm)*NN + lq*8];
            const unsigned short* brow = &vtb[(long)(f0 + lm)*NN + lq*8];
            f32x4 acc = {0.f, 0.f, 0.f, 0.f};
            #pragma unroll 4
            for (int kk = 0; kk < NN; kk += 32) {
                const bhalf8 a = *(const bhalf8*)&arow[kk];
                const bhalf8 b = *(const bhalf8*)&brow[kk];
                acc = __builtin_amdgcn_mfma_f32_16x16x32_bf16(a, b, acc, 0, 0, 0);
            }
            #pragma unroll
            for (int r = 0; r < 4; ++r) {
                const int i = it*16 + lq*4 + r;     // C/D: row=(l>>4)*4+reg
                const int f = f0 + lm;              //      col=l&15
                float s = acc[r];
                s = (s > 0.f) ? s : (__expf(s) - 1.f);
                out0[(long)i*FOUT + f] = s;
                unb [(long)i*FOUT + f] = f2b(s);
            }
        }
    }
    gridbar(bar, NB*4);

    // ================= P5: sim = un@un^T; c0 = bf16(sigmoid*ddb); row stats
    // 1024 virtual blocks of 256 thr (4 per real block), tile 64i x 64j.
    {
        const int vb = gid*4 + (tid >> 8);          // [0,1024)
        const int vt = tid & 255;
        const int i0 = (vb >> 5)*64, j0 = (vb & 31)*64;
        const int w2 = vt >> 6, l = vt & 63;
        const int lm = l & 15, lq = l >> 4;
        const int iw = i0 + w2*16;
        f32x4 acc[4] = {f32x4{0,0,0,0}, f32x4{0,0,0,0}, f32x4{0,0,0,0}, f32x4{0,0,0,0}};
        for (int kk = 0; kk < FOUT; kk += 32) {
            const bhalf8 a = *(const bhalf8*)&unb[(long)(iw + lm)*FOUT + kk + lq*8];
            #pragma unroll
            for (int c = 0; c < 4; ++c) {
                const bhalf8 b = *(const bhalf8*)&unb[(long)(j0 + c*16 + lm)*FOUT + kk + lq*8];
                acc[c] = __builtin_amdgcn_mfma_f32_16x16x32_bf16(a, b, acc[c], 0, 0, 0);
            }
        }
        float srow[4] = {0.f,0.f,0.f,0.f}, qrow[4] = {0.f,0.f,0.f,0.f};
        #pragma unroll
        for (int c = 0; c < 4; ++c) {
            #pragma unroll
            for (int r = 0; r < 4; ++r) {
                const int i = iw + lq*4 + r;
                const int j = j0 + c*16 + lm;
                const long idx = (long)i*NN + j;
                const float sg = 1.f / (1.f + __expf(-acc[c][r]));
                const float val = sg * b2f(ddb[idx]);
                fbuf_c0[idx] = f2b(val);            // c0 overlays fbuf (dead)
                srow[r] += val;
                qrow[r] = fmaf(val, val, qrow[r]);
            }
        }
        #pragma unroll
        for (int r = 0; r < 4; ++r) {
            #pragma unroll
            for (int m = 8; m >= 1; m >>= 1) {
                srow[r] += __shfl_xor(srow[r], m, 64);
                qrow[r] += __shfl_xor(qrow[r], m, 64);
            }
            if (lm == 0) {
                atomicAdd(&rowsum[iw + lq*4 + r], srow[r]);
                atomicAdd(&rowsq [iw + lq*4 + r], qrow[r]);
            }
        }
    }
    gridbar(bar, NB*5);

    // ================= P7: conn = norm(c0) + norm(c0)^T (stats inline)
    for (int tile = gid; tile < 1024; tile += NB) {
        const int i0 = (tile >> 5)*64, j0 = (tile & 31)*64;
        __syncthreads();                 // previous iteration's LT reads done
        if (tid < 64) {
            const float m = rowsum[j0 + tid] * (1.f/NN);
            sh.p7.muj[tid] = m;
            sh.p7.rsj[tid] = rsqrtf(rowsq[j0 + tid]*(1.f/NN) - m*m + 1e-5f);
        } else if (tid < 128) {
            const int rr = tid - 64;
            const float m = rowsum[i0 + rr] * (1.f/NN);
            sh.p7.mui[rr] = m;
            sh.p7.rii[rr] = rsqrtf(rowsq[i0 + rr]*(1.f/NN) - m*m + 1e-5f);
        }
        const int r  = tid >> 4;
        const int c4 = (tid & 15) * 4;
        {   // LT[i_local][j_local] = c0[j0+jl][i0+il]
            const ushort4 q = *(const ushort4*)&fbuf_c0[(long)(j0 + r)*NN + i0 + c4];
            sh.p7.LT[c4+0][r] = b2f(q.x); sh.p7.LT[c4+1][r] = b2f(q.y);
            sh.p7.LT[c4+2][r] = b2f(q.z); sh.p7.LT[c4+3][r] = b2f(q.w);
        }
        __syncthreads();
        {
            const int i = i0 + r;
            const ushort4 xb = *(const ushort4*)&fbuf_c0[(long)i*NN + j0 + c4];
            const float mi = sh.p7.mui[r], ri = sh.p7.rii[r];
            float4 o;
            o.x = (b2f(xb.x) - mi)*ri + (sh.p7.LT[r][c4+0] - sh.p7.muj[c4+0])*sh.p7.rsj[c4+0];
            o.y = (b2f(xb.y) - mi)*ri + (sh.p7.LT[r][c4+1] - sh.p7.muj[c4+1])*sh.p7.rsj[c4+1];
            o.z = (b2f(xb.z) - mi)*ri + (sh.p7.LT[r][c4+2] - sh.p7.muj[c4+2])*sh.p7.rsj[c4+2];
            o.w = (b2f(xb.w) - mi)*ri + (sh.p7.LT[r][c4+3] - sh.p7.muj[c4+3])*sh.p7.rsj[c4+3];
            *(float4*)&out1[(long)i*NN + j0 + c4] = o;
        }
    }
}

extern "C" void kernel_launch(void* const* d_in, const int* in_sizes, int n_in,
                              void* d_out, int out_size, void* d_ws, size_t ws_size,
                              hipStream_t stream)
{
    const float* x    = (const float*)d_in[0];
    const float* dist = (const float*)d_in[1];
    const float* bond = (const float*)d_in[2];
    // d_in[3] edge_direction: unused (only l=0 component couples; Y_0 = 1)
    const float* deg  = (const float*)d_in[4];
    const float* Wq   = (const float*)d_in[5];
    const float* Wk   = (const float*)d_in[6];
    const float* Wv   = (const float*)d_in[7];
    const float* wb   = (const float*)d_in[8];
    const float* wbc  = (const float*)d_in[9];
    const float* wg   = (const float*)d_in[10];

    float* out0 = (float*)d_out;            // updated_nodes: 2048*256 fp32
    float* out1 = out0 + (size_t)NN*FOUT;   // conn: 2048*2048 fp32

    char* w = (char*)d_ws;
    unsigned short* fbuf_c0 = (unsigned short*)(w);           //  8,388,608 B
    unsigned short* amb  = (unsigned short*)(w +  8388608);   //  8,388,608 B
    unsigned short* ddb  = (unsigned short*)(w + 16777216);   //  8,388,608 B
    unsigned short* vtb  = (unsigned short*)(w + 35651584);   //  1,048,576 B
    unsigned short* unb  = (unsigned short*)(w + 36700160);   //  1,048,576 B
    float* qk      = (float*)(w + 37748736);                  //     65,536 B
    float* D       = (float*)(w + 37814272);                  //     65,536 B
    float* rowsum  = (float*)(w + 37879808);                  //      8,192 B
    float* rowsq   = (float*)(w + 37888000);                  //      8,192 B
    unsigned* bar  = (unsigned*)(w + 37896192);               //        128 B

    hipMemsetAsync(bar, 0, 128, stream);
    hipLaunchKernelGGL(mega, dim3(NB), dim3(NT), 0, stream,
        x, dist, bond, deg, Wq, Wk, Wv, wb, wbc, wg,
        out0, out1, fbuf_c0, amb, ddb, vtb, unb, qk, D, rowsum, rowsq, bar);
}

// Round 4
// 240.543 us; speedup vs baseline: 2.2267x; 2.2267x over previous
//
#include <hip/hip_runtime.h>
#include <hip/hip_bf16.h>

#define NN 2048
#define FIN 256
#define FOUT 256
#define HH 8

typedef short bhalf8 __attribute__((ext_vector_type(8)));   // 8 bf16
typedef float f32x4  __attribute__((ext_vector_type(4)));   // MFMA acc

__device__ __forceinline__ unsigned short f2b(float f) {
    __hip_bfloat16 h = __float2bfloat16(f);
    return *reinterpret_cast<unsigned short*>(&h);
}
__device__ __forceinline__ float b2f(unsigned short u) {
    __hip_bfloat16 h = *reinterpret_cast<__hip_bfloat16*>(&u);
    return __bfloat162float(h);
}

// ------------------- K1: qk, vtb (bf16 transpose direct), zero D/rowsum/rowsq
// 4 nodes per block; Wv L2-resident across blocks. grid 512 x 256thr.
__global__ __launch_bounds__(256) void k1_qkv(
    const float* __restrict__ x, const float* __restrict__ Wq,
    const float* __restrict__ Wk, const float* __restrict__ Wv,
    unsigned short* __restrict__ vtb, float* __restrict__ qk,
    float* __restrict__ D, float* __restrict__ rowsum, float* __restrict__ rowsq)
{
    const int ib = blockIdx.x * 4;
    const int t  = threadIdx.x;
    // zero accumulators for this launch (stream-ordered before k2/k5)
    {
        const int tp = blockIdx.x*256 + t;
        if      (tp < 16384) D[tp] = 0.f;
        else if (tp < 18432) rowsum[tp - 16384] = 0.f;
        else if (tp < 20480) rowsq [tp - 18432] = 0.f;
    }
    __shared__ float xs[4][FIN];
    __shared__ float part[256];
    #pragma unroll
    for (int n = 0; n < 4; ++n) xs[n][t] = x[(long)(ib+n)*FIN + t];
    __syncthreads();
    float a0 = 0.f, a1 = 0.f, a2 = 0.f, a3 = 0.f;
    #pragma unroll 4
    for (int c = 0; c < FIN; ++c) {
        const float wv = Wv[c*FOUT + t];
        a0 = fmaf(xs[0][c], wv, a0); a1 = fmaf(xs[1][c], wv, a1);
        a2 = fmaf(xs[2][c], wv, a2); a3 = fmaf(xs[3][c], wv, a3);
    }
    // vT_bf16[f][k], 4 consecutive k per thread (8B aligned: ib%4==0)
    ushort4 uv;
    uv.x = f2b(a0 * 0.0625f); uv.y = f2b(a1 * 0.0625f);
    uv.z = f2b(a2 * 0.0625f); uv.w = f2b(a3 * 0.0625f);
    *(ushort4*)&vtb[(long)t*NN + ib] = uv;
    {
        const int n = t >> 6, h = t & 7, seg = (t >> 3) & 7;
        float a = 0.f;
        for (int c = seg*32; c < seg*32 + 32; ++c)
            a = fmaf(xs[n][c], Wq[c*HH + h] + Wk[c*HH + h], a);
        part[t] = a;
    }
    __syncthreads();
    if (t < 32) {
        const int n = t >> 3, h = t & 7;
        float a = 0.f;
        #pragma unroll
        for (int s2 = 0; s2 < 8; ++s2) a += part[n*64 + s2*8 + h];
        qk[(ib+n)*HH + h] = a * (0.0625f * 0.35355339059327373f); // *scale/sqrt(8)
    }
}

// ------------------------------------------------- K2: denoms + f-field + dd
// Tile 32i x 256j, grid (8,64)=512 blocks (2/CU, 8 waves/CU). float4 loads.
// f[i,j] = masked ? -inf : cb*bond+cg*dist (bf16);  ddb[i,j] = bf16(-dist*deg)
// D[j,h] += sum_i exp(leaky(qk[i,h] + f[i,j]))
__global__ __launch_bounds__(256) void k2_denom(
    const float* __restrict__ bond, const float* __restrict__ dist,
    const float* __restrict__ deg, const float* __restrict__ qk,
    const float* __restrict__ wb, const float* __restrict__ wbc,
    const float* __restrict__ wg, float* __restrict__ D,
    unsigned short* __restrict__ fbuf, unsigned short* __restrict__ ddb)
{
    const float cb = wb[0] * wbc[0];
    const float cg = wg[0];
    const int t  = threadIdx.x;
    const int tx = t & 63;              // j-quad
    const int ty = t >> 6;              // 0..3 (i-subtile, 8 i each)
    const int j0 = blockIdx.x * 256;
    const int i0 = blockIdx.y * 32;
    const int j  = j0 + tx*4;
    __shared__ float qs[32*8];          // 1 KB
    __shared__ float red[4][2048];      // 32 KB
    if (t < 256) { /* all */ }
    for (int p = t; p < 256; p += 256) qs[p] = qk[i0*8 + p];
    __syncthreads();
    float acc[4][8];
    #pragma unroll
    for (int jj = 0; jj < 4; ++jj)
        #pragma unroll
        for (int h = 0; h < 8; ++h) acc[jj][h] = 0.f;
    const int ibase = i0 + ty*8;
    #pragma unroll
    for (int ii = 0; ii < 8; ++ii) {
        const long idx = (long)(ibase + ii)*NN + j;
        const float4 dv = *(const float4*)&dist[idx];
        const float4 bv = *(const float4*)&bond[idx];
        const float4 gv = *(const float4*)&deg[idx];
        ushort4 fb, db;
        fb.x = f2b((gv.x > 0.f) ? fmaf(cb, bv.x, cg*dv.x) : -__builtin_inff());
        fb.y = f2b((gv.y > 0.f) ? fmaf(cb, bv.y, cg*dv.y) : -__builtin_inff());
        fb.z = f2b((gv.z > 0.f) ? fmaf(cb, bv.z, cg*dv.z) : -__builtin_inff());
        fb.w = f2b((gv.w > 0.f) ? fmaf(cb, bv.w, cg*dv.w) : -__builtin_inff());
        db.x = f2b(-dv.x * gv.x); db.y = f2b(-dv.y * gv.y);
        db.z = f2b(-dv.z * gv.z); db.w = f2b(-dv.w * gv.w);
        *(ushort4*)&fbuf[idx] = fb;
        *(ushort4*)&ddb[idx]  = db;
        float s[4];
        s[0] = b2f(fb.x); s[1] = b2f(fb.y); s[2] = b2f(fb.z); s[3] = b2f(fb.w);
        const float* qrow = &qs[(ty*8 + ii)*8];
        #pragma unroll
        for (int h = 0; h < 8; ++h) {
            const float q = qrow[h];
            #pragma unroll
            for (int jj = 0; jj < 4; ++jj) {
                float r = q + s[jj];
                r = fmaxf(r, 0.2f*r);       // leaky_relu(r, 0.2)
                acc[jj][h] += __expf(r);    // masked: exp(-inf) = 0
            }
        }
    }
    #pragma unroll
    for (int jj = 0; jj < 4; ++jj)
        #pragma unroll
        for (int h = 0; h < 8; ++h) red[ty][(tx*4 + jj)*8 + h] = acc[jj][h];
    __syncthreads();
    for (int p = t; p < 2048; p += 256) {
        const float ssum = red[0][p] + red[1][p] + red[2][p] + red[3][p];
        atomicAdd(&D[j0*8 + p], ssum);
    }
}

// --------------------------- K3: attn_mean -> bf16 (tile 32i x 256j, grid 512)
__global__ __launch_bounds__(256) void k3_attnmean(
    const unsigned short* __restrict__ fbuf, const float* __restrict__ qk,
    const float* __restrict__ D, unsigned short* __restrict__ amb)
{
    const int t  = threadIdx.x;
    const int tx = t & 63;
    const int ty = t >> 6;
    const int j0 = blockIdx.x * 256;
    const int i0 = blockIdx.y * 32;
    const int j  = j0 + tx*4;
    __shared__ float qs[32*8];
    for (int p = t; p < 256; p += 256) qs[p] = qk[i0*8 + p];
    __syncthreads();
    float invD[4][8];
    #pragma unroll
    for (int jj = 0; jj < 4; ++jj)
        #pragma unroll
        for (int h = 0; h < 8; ++h)
            invD[jj][h] = 0.125f / fmaxf(D[(j + jj)*8 + h], 1e-30f);
    const int ibase = i0 + ty*8;
    #pragma unroll
    for (int ii = 0; ii < 8; ++ii) {
        const long idx = (long)(ibase + ii)*NN + j;
        const ushort4 fb = *(const ushort4*)&fbuf[idx];
        float s[4];
        s[0] = b2f(fb.x); s[1] = b2f(fb.y); s[2] = b2f(fb.z); s[3] = b2f(fb.w);
        float o[4] = {0.f, 0.f, 0.f, 0.f};
        const float* qrow = &qs[(ty*8 + ii)*8];
        #pragma unroll
        for (int h = 0; h < 8; ++h) {
            const float q = qrow[h];
            #pragma unroll
            for (int jj = 0; jj < 4; ++jj) {
                float r = q + s[jj];
                r = fmaxf(r, 0.2f*r);
                o[jj] = fmaf(__expf(r), invD[jj][h], o[jj]);  // masked -> 0
            }
        }
        ushort4 ob;
        ob.x = f2b(o[0]); ob.y = f2b(o[1]); ob.z = f2b(o[2]); ob.w = f2b(o[3]);
        *(ushort4*)&amb[idx] = ob;
    }
}

// --------------- K4: aggregated = amb @ vtb^T (full K) + elu -> out0, unb
// grid 512 x 256thr; 4 waves/block, each wave one 16i x 16f tile.
__global__ __launch_bounds__(256) void k4_aggr(
    const unsigned short* __restrict__ amb,
    const unsigned short* __restrict__ vtb,
    float* __restrict__ out0, unsigned short* __restrict__ unb)
{
    const int w = threadIdx.x >> 6, lane = threadIdx.x & 63;
    const int vw = blockIdx.x*4 + w;            // [0,2048)
    const int it = vw >> 4;                     // i-tile [0,128)
    const int f0 = (vw & 15) * 16;              // f-tile
    const int lm = lane & 15, lq = lane >> 4;
    const unsigned short* arow = &amb[(long)(it*16 + lm)*NN + lq*8];
    const unsigned short* brow = &vtb[(long)(f0 + lm)*NN + lq*8];
    f32x4 acc = {0.f, 0.f, 0.f, 0.f};
    #pragma unroll 4
    for (int kk = 0; kk < NN; kk += 32) {
        const bhalf8 a = *(const bhalf8*)&arow[kk];
        const bhalf8 b = *(const bhalf8*)&brow[kk];
        acc = __builtin_amdgcn_mfma_f32_16x16x32_bf16(a, b, acc, 0, 0, 0);
    }
    #pragma unroll
    for (int r = 0; r < 4; ++r) {
        const int i = it*16 + lq*4 + r;         // C/D: row=(l>>4)*4+reg
        const int f = f0 + lm;                  //      col=l&15
        float s = acc[r];
        s = (s > 0.f) ? s : (__expf(s) - 1.f);
        out0[(long)i*FOUT + f] = s;
        unb [(long)i*FOUT + f] = f2b(s);
    }
}

// -------- K5: sim = un@un^T via MFMA; c0 = bf16(sigmoid(sim)*ddb); row stats
__global__ __launch_bounds__(256) void k5_sim(
    const unsigned short* __restrict__ unb, const unsigned short* __restrict__ ddb,
    unsigned short* __restrict__ c0,
    float* __restrict__ rowsum, float* __restrict__ rowsq)
{
    const int i0 = blockIdx.y * 64;
    const int j0 = blockIdx.x * 64;
    const int w  = threadIdx.x >> 6;
    const int l  = threadIdx.x & 63;
    const int lm = l & 15, lq = l >> 4;
    const int iw = i0 + w*16;
    f32x4 acc[4] = {f32x4{0,0,0,0}, f32x4{0,0,0,0}, f32x4{0,0,0,0}, f32x4{0,0,0,0}};
    for (int kk = 0; kk < FOUT; kk += 32) {
        const bhalf8 a = *(const bhalf8*)&unb[(long)(iw + lm)*FOUT + kk + lq*8];
        #pragma unroll
        for (int c = 0; c < 4; ++c) {
            const bhalf8 b = *(const bhalf8*)&unb[(long)(j0 + c*16 + lm)*FOUT + kk + lq*8];
            acc[c] = __builtin_amdgcn_mfma_f32_16x16x32_bf16(a, b, acc[c], 0, 0, 0);
        }
    }
    float srow[4] = {0.f,0.f,0.f,0.f}, qrow[4] = {0.f,0.f,0.f,0.f};
    #pragma unroll
    for (int c = 0; c < 4; ++c) {
        #pragma unroll
        for (int r = 0; r < 4; ++r) {
            const int i = iw + lq*4 + r;
            const int j = j0 + c*16 + lm;
            const long idx = (long)i*NN + j;
            const float sg = 1.f / (1.f + __expf(-acc[c][r]));
            const float val = sg * b2f(ddb[idx]);        // ddb = -dist*deg
            c0[idx] = f2b(val);
            srow[r] += val;
            qrow[r] = fmaf(val, val, qrow[r]);
        }
    }
    #pragma unroll
    for (int r = 0; r < 4; ++r) {
        #pragma unroll
        for (int m = 8; m >= 1; m >>= 1) {
            srow[r] += __shfl_xor(srow[r], m, 64);
            qrow[r] += __shfl_xor(qrow[r], m, 64);
        }
        if (lm == 0) {
            atomicAdd(&rowsum[iw + lq*4 + r], srow[r]);
            atomicAdd(&rowsq [iw + lq*4 + r], qrow[r]);
        }
    }
}

// -------- K7: conn = norm(c0) + norm(c0)^T; stats computed from rowsum/rowsq
__global__ __launch_bounds__(256) void k7_conn(
    const unsigned short* __restrict__ c0, const float* __restrict__ rowsum,
    const float* __restrict__ rowsq, float* __restrict__ out1)
{
    const int i0 = blockIdx.y * 64;
    const int j0 = blockIdx.x * 64;
    const int t  = threadIdx.x;
    __shared__ float LT[64][68];     // LT[i_local][j_local] = c0[j0+jl][i0+il]
    __shared__ float mui[64], rii[64], muj[64], rsj[64];
    const int r  = t >> 4;
    const int c4 = (t & 15) * 4;
    if (t < 64) {
        const float m = rowsum[j0 + t] * (1.f/NN);
        muj[t] = m;
        rsj[t] = rsqrtf(rowsq[j0 + t]*(1.f/NN) - m*m + 1e-5f);
    } else if (t < 128) {
        const int rr = t - 64;
        const float m = rowsum[i0 + rr] * (1.f/NN);
        mui[rr] = m;
        rii[rr] = rsqrtf(rowsq[i0 + rr]*(1.f/NN) - m*m + 1e-5f);
    }
    #pragma unroll
    for (int p = 0; p < 4; ++p) {
        const int jl = r + p*16;
        const ushort4 q = *(const ushort4*)&c0[(long)(j0 + jl)*NN + i0 + c4];
        LT[c4+0][jl] = b2f(q.x); LT[c4+1][jl] = b2f(q.y);
        LT[c4+2][jl] = b2f(q.z); LT[c4+3][jl] = b2f(q.w);
    }
    __syncthreads();
    #pragma unroll
    for (int p = 0; p < 4; ++p) {
        const int rr = r + p*16;
        const int i  = i0 + rr;
        const ushort4 xb = *(const ushort4*)&c0[(long)i*NN + j0 + c4];
        const float mi = mui[rr], ri = rii[rr];
        float4 o;
        o.x = (b2f(xb.x) - mi)*ri + (LT[rr][c4+0] - muj[c4+0])*rsj[c4+0];
        o.y = (b2f(xb.y) - mi)*ri + (LT[rr][c4+1] - muj[c4+1])*rsj[c4+1];
        o.z = (b2f(xb.z) - mi)*ri + (LT[rr][c4+2] - muj[c4+2])*rsj[c4+2];
        o.w = (b2f(xb.w) - mi)*ri + (LT[rr][c4+3] - muj[c4+3])*rsj[c4+3];
        *(float4*)&out1[(long)i*NN + j0 + c4] = o;
    }
}

extern "C" void kernel_launch(void* const* d_in, const int* in_sizes, int n_in,
                              void* d_out, int out_size, void* d_ws, size_t ws_size,
                              hipStream_t stream)
{
    const float* x    = (const float*)d_in[0];
    const float* dist = (const float*)d_in[1];
    const float* bond = (const float*)d_in[2];
    // d_in[3] edge_direction: unused (only l=0 component couples; Y_0 = 1)
    const float* deg  = (const float*)d_in[4];
    const float* Wq   = (const float*)d_in[5];
    const float* Wk   = (const float*)d_in[6];
    const float* Wv   = (const float*)d_in[7];
    const float* wb   = (const float*)d_in[8];
    const float* wbc  = (const float*)d_in[9];
    const float* wg   = (const float*)d_in[10];

    float* out0 = (float*)d_out;            // updated_nodes: 2048*256 fp32
    float* out1 = out0 + (size_t)NN*FOUT;   // conn: 2048*2048 fp32

    // Workspace ~27.4 MB. c0 overlays fbuf (dead after k3).
    char* w = (char*)d_ws;
    unsigned short* fbuf_c0 = (unsigned short*)(w);           //  8,388,608 B
    unsigned short* amb  = (unsigned short*)(w +  8388608);   //  8,388,608 B
    unsigned short* ddb  = (unsigned short*)(w + 16777216);   //  8,388,608 B
    unsigned short* vtb  = (unsigned short*)(w + 25165824);   //  1,048,576 B
    unsigned short* unb  = (unsigned short*)(w + 26214400);   //  1,048,576 B
    float* qk      = (float*)(w + 27262976);                  //     65,536 B
    float* D       = (float*)(w + 27328512);                  //     65,536 B
    float* rowsum  = (float*)(w + 27394048);                  //      8,192 B
    float* rowsq   = (float*)(w + 27402240);                  //      8,192 B

    k1_qkv<<<NN/4, 256, 0, stream>>>(x, Wq, Wk, Wv, vtb, qk, D, rowsum, rowsq);
    dim3 g23(NN/256, NN/32);
    k2_denom<<<g23, 256, 0, stream>>>(bond, dist, deg, qk, wb, wbc, wg, D, fbuf_c0, ddb);
    k3_attnmean<<<g23, 256, 0, stream>>>(fbuf_c0, qk, D, amb);
    k4_aggr<<<NN/4, 256, 0, stream>>>(amb, vtb, out0, unb);
    dim3 g5(NN/64, NN/64);
    k5_sim<<<g5, 256, 0, stream>>>(unb, ddb, fbuf_c0, rowsum, rowsq);
    k7_conn<<<g5, 256, 0, stream>>>(fbuf_c0, rowsum, rowsq, out1);
}